// Round 3
// baseline (309.218 us; speedup 1.0000x reference)
//
#include <hip/hip_runtime.h>

namespace {
constexpr int   S_GRID   = 14;
constexpr int   CH       = 30;
constexpr float L_COORD  = 5.0f;
constexpr float L_NOOBJ  = 0.5f;
constexpr float BOX_EPS  = 1e-20f;
constexpr int   BLOCK    = 256;   // threads per block (4 waves)
constexpr int   TILE     = 64;    // cells per block; wave 0 computes them
}

// Block stages TILE=64 cells (1920 floats/tensor) global->LDS with coalesced
// float4 loads, then wave 0 computes the 64 per-cell losses from LDS and
// shuffle-reduces to one atomicAdd. LDS = 2*64*30*4 = 15360 B/block ->
// residency thread-capped at 8 blocks/CU = 32 waves/CU (100% occupancy cap),
// 4x the previous 61 KiB version. Waves 1-3 exit right after the barrier.
__global__ __launch_bounds__(BLOCK) void yolo_loss_kernel(
    const float* __restrict__ pred,
    const float* __restrict__ tgt,
    float* __restrict__ out,
    float inv_n)
{
    __shared__ float sp[TILE * CH];   // 1920 floats
    __shared__ float st[TILE * CH];

    const int tid = threadIdx.x;
    const size_t base = (size_t)blockIdx.x * (TILE * CH);

    // ---- stage global -> LDS, coalesced float4 (block base 7680B-aligned)
    const float4* gp4 = reinterpret_cast<const float4*>(pred + base);
    const float4* gt4 = reinterpret_cast<const float4*>(tgt + base);
    float4* sp4 = reinterpret_cast<float4*>(sp);
    float4* st4 = reinterpret_cast<float4*>(st);
    constexpr int NV4 = TILE * CH / 4;  // 480
    // iter 0: all 256 threads; iter 1: threads 0..223
    sp4[tid] = gp4[tid];
    st4[tid] = gt4[tid];
    if (tid < NV4 - BLOCK) {
        sp4[tid + BLOCK] = gp4[tid + BLOCK];
        st4[tid + BLOCK] = gt4[tid + BLOCK];
    }
    __syncthreads();

    // ---- wave 0 computes; waves 1-3 exit (no further barriers)
    if (tid >= TILE) return;

    // cell tid: 30 floats at 120B offset -> 8B aligned, float2 LDS reads ok.
    // Lane stride 30 words -> gcd(30,32)=2, 4-way conflict over 64 lanes (ok).
    const float* p = sp + tid * CH;
    const float* t = st + tid * CH;
    float pv[CH], tv[CH];
    #pragma unroll
    for (int j = 0; j < CH / 2; ++j) {
        float2 a = reinterpret_cast<const float2*>(p)[j];
        pv[2 * j] = a.x; pv[2 * j + 1] = a.y;
        float2 b = reinterpret_cast<const float2*>(t)[j];
        tv[2 * j] = b.x; tv[2 * j + 1] = b.y;
    }

    const float objf   = ((tv[4] + tv[9]) > 0.0f) ? 1.0f : 0.0f;
    const float noobjf = 1.0f - objf;

    // no-object confidence loss
    const float d4 = pv[4] - tv[4];
    const float d9 = pv[9] - tv[9];
    const float no_obj = noobjf * (d4 * d4 + d9 * d9);

    // class loss (channels 10..29)
    float cls = 0.0f;
    #pragma unroll
    for (int j = 10; j < CH; ++j) {
        const float d = pv[j] - tv[j];
        cls += d * d;
    }
    cls *= objf;

    // per-box elementwise IoU, corner form as in reference
    float iou[2];
    constexpr float invS = 1.0f / (float)S_GRID;
    #pragma unroll
    for (int b = 0; b < 2; ++b) {
        const float* bp = pv + 5 * b;
        const float* bt = tv + 5 * b;
        const float txc = bt[0] * invS, tyc = bt[1] * invS;
        const float tx1 = txc - 0.5f * bt[2], tx2 = txc + 0.5f * bt[2];
        const float ty1 = tyc - 0.5f * bt[3], ty2 = tyc + 0.5f * bt[3];
        const float pxc = bp[0] * invS, pyc = bp[1] * invS;
        const float px1 = pxc - 0.5f * bp[2], px2 = pxc + 0.5f * bp[2];
        const float py1 = pyc - 0.5f * bp[3], py2 = pyc + 0.5f * bp[3];
        const float iw = fmaxf(fminf(tx2, px2) - fmaxf(tx1, px1), 0.0f);
        const float ih = fmaxf(fminf(ty2, py2) - fmaxf(ty1, py1), 0.0f);
        const float inter  = iw * ih;
        const float area_t = (tx2 - tx1) * (ty2 - ty1);
        const float area_p = (px2 - px1) * (py2 - py1);
        iou[b] = inter / (area_t + area_p - inter);
    }

    // responsible-box selection: a0 = iou0 > iou1 ; a1 = float(a0) <= iou1
    const bool  a0   = iou[0] > iou[1];
    const bool  a1   = (a0 ? 1.0f : 0.0f) <= iou[1];
    const float sel0 = a0 ? 1.0f : 0.0f;
    const float sel1 = a1 ? 1.0f : 0.0f;

    float contain = 0.0f, regr = 0.0f;
    #pragma unroll
    for (int b = 0; b < 2; ++b) {
        const float w  = objf * (b == 0 ? sel0 : sel1);
        const float* bp = pv + 5 * b;
        const float* bt = tv + 5 * b;
        const float dc = bp[4] - iou[b];
        contain += w * dc * dc;
        const float dx  = bp[0] - bt[0];
        const float dy  = bp[1] - bt[1];
        const float dsw = sqrtf(bp[2] + BOX_EPS) - sqrtf(bt[2] + BOX_EPS);
        const float dsh = sqrtf(bp[3] + BOX_EPS) - sqrtf(bt[3] + BOX_EPS);
        regr += w * (dx * dx + dy * dy + dsw * dsw + dsh * dsh);
    }

    float acc = L_COORD * regr + contain + L_NOOBJ * no_obj + cls;

    // ---- wave-0 shuffle reduction over its 64 lanes, one atomic per block
    #pragma unroll
    for (int off = 32; off > 0; off >>= 1)
        acc += __shfl_down(acc, off, 64);
    if (tid == 0) atomicAdd(out, acc * inv_n);
}

extern "C" void kernel_launch(void* const* d_in, const int* in_sizes, int n_in,
                              void* d_out, int out_size, void* d_ws, size_t ws_size,
                              hipStream_t stream) {
    const float* pred = (const float*)d_in[0];
    const float* tgt  = (const float*)d_in[1];
    float* out = (float*)d_out;

    const int ncells  = in_sizes[0] / CH;             // 4096*14*14 = 802816
    const int n_batch = ncells / (S_GRID * S_GRID);   // 4096
    const int grid    = ncells / TILE;                // 12544 (exact)

    // harness re-poisons d_out to 0xAA before every timed launch
    hipMemsetAsync(out, 0, (size_t)out_size * sizeof(float), stream);
    yolo_loss_kernel<<<grid, BLOCK, 0, stream>>>(pred, tgt, out,
                                                 1.0f / (float)n_batch);
}

// Round 5
// 210.838 us; speedup vs baseline: 1.4666x; 1.4666x over previous
//
#include <hip/hip_runtime.h>

namespace {
constexpr int   S_GRID   = 14;
constexpr int   CH       = 30;
constexpr float L_COORD  = 5.0f;
constexpr float L_NOOBJ  = 0.5f;
constexpr float BOX_EPS  = 1e-20f;
constexpr int   BLOCK    = 256;
constexpr int   NSLOT    = 256;   // hashed partial-sum slots
constexpr int   SLOT_STRIDE = 16; // floats between slots (64B -> own cache line)
}

// One thread per cell, direct global loads (no LDS staging, no barrier before
// reduce). Per-instruction lane stride is 120B, but each wave's footprint is
// a contiguous 7.5KB/tensor, so L1/L2 fetch every line exactly once -> ideal
// HBM traffic without the LDS round-trip. Block reduces via shuffles and one
// atomicAdd into a per-(blockIdx%256) line-separated slot (max ~13 serialized
// adds/slot vs 12544 same-address atomics previously).
__global__ __launch_bounds__(BLOCK) void yolo_main_kernel(
    const float* __restrict__ pred,
    const float* __restrict__ tgt,
    float* __restrict__ partial)
{
    __shared__ float wsum[BLOCK / 64];

    const int tid  = threadIdx.x;
    const size_t cell = (size_t)blockIdx.x * BLOCK + tid;

    const float* p = pred + cell * CH;  // 120B stride, 8B aligned
    const float* t = tgt  + cell * CH;

    float pv[CH], tv[CH];
    #pragma unroll
    for (int j = 0; j < CH / 2; ++j) {
        float2 a = reinterpret_cast<const float2*>(p)[j];
        pv[2 * j] = a.x; pv[2 * j + 1] = a.y;
        float2 b = reinterpret_cast<const float2*>(t)[j];
        tv[2 * j] = b.x; tv[2 * j + 1] = b.y;
    }

    const float objf   = ((tv[4] + tv[9]) > 0.0f) ? 1.0f : 0.0f;
    const float noobjf = 1.0f - objf;

    // no-object confidence loss
    const float d4 = pv[4] - tv[4];
    const float d9 = pv[9] - tv[9];
    const float no_obj = noobjf * (d4 * d4 + d9 * d9);

    // class loss (channels 10..29)
    float cls = 0.0f;
    #pragma unroll
    for (int j = 10; j < CH; ++j) {
        const float d = pv[j] - tv[j];
        cls += d * d;
    }
    cls *= objf;

    // per-box elementwise IoU, corner form as in reference
    float iou[2];
    constexpr float invS = 1.0f / (float)S_GRID;
    #pragma unroll
    for (int b = 0; b < 2; ++b) {
        const float* bp = pv + 5 * b;
        const float* bt = tv + 5 * b;
        const float txc = bt[0] * invS, tyc = bt[1] * invS;
        const float tx1 = txc - 0.5f * bt[2], tx2 = txc + 0.5f * bt[2];
        const float ty1 = tyc - 0.5f * bt[3], ty2 = tyc + 0.5f * bt[3];
        const float pxc = bp[0] * invS, pyc = bp[1] * invS;
        const float px1 = pxc - 0.5f * bp[2], px2 = pxc + 0.5f * bp[2];
        const float py1 = pyc - 0.5f * bp[3], py2 = pyc + 0.5f * bp[3];
        const float iw = fmaxf(fminf(tx2, px2) - fmaxf(tx1, px1), 0.0f);
        const float ih = fmaxf(fminf(ty2, py2) - fmaxf(ty1, py1), 0.0f);
        const float inter  = iw * ih;
        const float area_t = (tx2 - tx1) * (ty2 - ty1);
        const float area_p = (px2 - px1) * (py2 - py1);
        iou[b] = inter / (area_t + area_p - inter);
    }

    // responsible-box selection: a0 = iou0 > iou1 ; a1 = float(a0) <= iou1
    const bool  a0   = iou[0] > iou[1];
    const bool  a1   = (a0 ? 1.0f : 0.0f) <= iou[1];
    const float sel0 = a0 ? 1.0f : 0.0f;
    const float sel1 = a1 ? 1.0f : 0.0f;

    float contain = 0.0f, regr = 0.0f;
    #pragma unroll
    for (int b = 0; b < 2; ++b) {
        const float w  = objf * (b == 0 ? sel0 : sel1);
        const float* bp = pv + 5 * b;
        const float* bt = tv + 5 * b;
        const float dc = bp[4] - iou[b];
        contain += w * dc * dc;
        const float dx  = bp[0] - bt[0];
        const float dy  = bp[1] - bt[1];
        const float dsw = sqrtf(bp[2] + BOX_EPS) - sqrtf(bt[2] + BOX_EPS);
        const float dsh = sqrtf(bp[3] + BOX_EPS) - sqrtf(bt[3] + BOX_EPS);
        regr += w * (dx * dx + dy * dy + dsw * dsw + dsh * dsh);
    }

    float acc = L_COORD * regr + contain + L_NOOBJ * no_obj + cls;

    // ---- block reduction: per-wave shuffles, cross-wave via LDS
    #pragma unroll
    for (int off = 32; off > 0; off >>= 1)
        acc += __shfl_down(acc, off, 64);
    const int lane = tid & 63;
    const int wid  = tid >> 6;
    if (lane == 0) wsum[wid] = acc;
    __syncthreads();
    if (tid == 0) {
        const float s = (wsum[0] + wsum[1]) + (wsum[2] + wsum[3]);
        atomicAdd(&partial[(blockIdx.x & (NSLOT - 1)) * SLOT_STRIDE], s);
    }
}

// 256 partial slots -> single scalar output (plain store, no atomic)
__global__ __launch_bounds__(NSLOT) void yolo_finalize_kernel(
    const float* __restrict__ partial,
    float* __restrict__ out,
    float inv_n)
{
    __shared__ float wsum[NSLOT / 64];
    const int tid = threadIdx.x;
    float v = partial[tid * SLOT_STRIDE];
    #pragma unroll
    for (int off = 32; off > 0; off >>= 1)
        v += __shfl_down(v, off, 64);
    const int lane = tid & 63;
    const int wid  = tid >> 6;
    if (lane == 0) wsum[wid] = v;
    __syncthreads();
    if (tid == 0)
        out[0] = ((wsum[0] + wsum[1]) + (wsum[2] + wsum[3])) * inv_n;
}

extern "C" void kernel_launch(void* const* d_in, const int* in_sizes, int n_in,
                              void* d_out, int out_size, void* d_ws, size_t ws_size,
                              hipStream_t stream) {
    const float* pred = (const float*)d_in[0];
    const float* tgt  = (const float*)d_in[1];
    float* out     = (float*)d_out;
    float* partial = (float*)d_ws;    // NSLOT*SLOT_STRIDE floats = 16 KB

    const int ncells  = in_sizes[0] / CH;             // 4096*14*14 = 802816
    const int n_batch = ncells / (S_GRID * S_GRID);   // 4096
    const int grid    = ncells / BLOCK;               // 3136 (exact)

    // d_ws is re-poisoned to 0xAA before every timed launch
    hipMemsetAsync(partial, 0, NSLOT * SLOT_STRIDE * sizeof(float), stream);
    yolo_main_kernel<<<grid, BLOCK, 0, stream>>>(pred, tgt, partial);
    yolo_finalize_kernel<<<1, NSLOT, 0, stream>>>(partial, out,
                                                  1.0f / (float)n_batch);
}